// Round 16
// baseline (326.247 us; speedup 1.0000x reference)
//
#include <hip/hip_runtime.h>
#include <math.h>

#define NT 512           // 8 waves
#define MB 64            // queries per block
#define MTOT 131072
#define IMG_H 384
#define IMG_W 512
#define H8 48
#define W8 64
#define H16 24
#define W16 32

#define SAB 136          // ab0/ab1/hb row stride (u16)
#define SHB 136
#define SPE 40           // pe row stride (u16), global scratch
#define SWG 128          // wg row stride (u16), global scratch

typedef _Float16 half8_t __attribute__((ext_vector_type(8)));
typedef _Float16 half4_t __attribute__((ext_vector_type(4)));
typedef float f32x4_t __attribute__((ext_vector_type(4)));
typedef unsigned short u16;

// packed weight fragment order: ((nt*KT + kt)*64 + lane)*8 + j
// element = W[kt*32 + (lane>>4)*8 + j][nt*16 + (lane&15)]
// sections: PP1 | MEGA1(WA 256x256) | S8(f1_w2) | MEGA2(WB) | S15(f2_w2) | HW1 | HW2
#define PW_PP1    0
#define PW_MEGA1  12288
#define PW_S8     77824
#define PW_MEGA2  110592
#define PW_S15    176128
#define PW_HW1    208896
#define PW_HW2    229376
#define PW_END    237568
#define FT8_OFF   PW_END
#define FT8_CNT   (2*H8*W8*128)
#define FT16_OFF  (FT8_OFF + FT8_CNT)
#define FT16_CNT  (2*H16*W16*128)
#define F32_OFF   (FT16_OFF + FT16_CNT)   // f32 region (u16 index, even)
// f32 region (float idx): Wbot1[0,16384) Wph2s[16384,32768) bf1[32768,32896)
//                         bA[32896,33152) bB[33152,33408)
#define PEG_OFF   (F32_OFF + 2*33408)     // u16 [2048][64][40]
#define PEG_CNT   (2048*MB*SPE)
#define CBG_OFF   (PEG_OFF + PEG_CNT)     // f32 [2048][64][2]
#define WG_OFF    (CBG_OFF + 2*2048*MB*2) // u16 [2048][64][128]

__device__ __forceinline__ u16 tohalf(float v) {
  return __builtin_bit_cast(u16, (_Float16)v);
}
// tanh-form gelu; |err vs exact erf-gelu| < 3e-3
__device__ __forceinline__ float geluf(float x) {
  float x2 = x * x;
  float t = x * fmaf(x2, 0.0713548162726f, 1.5957691216057308f);
  float e = __expf(-t);
  return x * __builtin_amdgcn_rcpf(1.0f + e);
}

__device__ __forceinline__ float bilin_plane(const float* __restrict__ plane,
                                             int Wd, int Hd, float x, float y) {
  x = fminf(fmaxf(x, 0.f), (float)(Wd - 1));
  y = fminf(fmaxf(y, 0.f), (float)(Hd - 1));
  float x0f = floorf(x), y0f = floorf(y);
  int x0 = (int)x0f, y0 = (int)y0f;
  int x1 = min(x0 + 1, Wd - 1), y1 = min(y0 + 1, Hd - 1);
  float wx = x - x0f, wy = y - y0f;
  const float* r0 = plane + y0 * Wd;
  const float* r1 = plane + y1 * Wd;
  float v00 = r0[x0], v01 = r0[x1], v10 = r1[x0], v11 = r1[x1];
  float top = v00 + wx * (v01 - v00);
  float bot = v10 + wx * (v11 - v10);
  return top + wy * (bot - top);
}

// bilinear gather of 8 fp16 channels, packed-f16 interpolation
__device__ __forceinline__ void featSample(const u16* __restrict__ ft, int Wd, int Hd,
                                           float x, float y, u16* dstRow, int i16) {
  x = fminf(fmaxf(x, 0.f), (float)(Wd - 1));
  y = fminf(fmaxf(y, 0.f), (float)(Hd - 1));
  float x0f = floorf(x), y0f = floorf(y);
  int x0 = (int)x0f, y0 = (int)y0f;
  int x1 = min(x0 + 1, Wd - 1), y1 = min(y0 + 1, Hd - 1);
  _Float16 wx = (_Float16)(x - x0f), wy = (_Float16)(y - y0f);
  half8_t v00 = *reinterpret_cast<const half8_t*>(ft + (y0 * Wd + x0) * 128 + i16 * 8);
  half8_t v01 = *reinterpret_cast<const half8_t*>(ft + (y0 * Wd + x1) * 128 + i16 * 8);
  half8_t v10 = *reinterpret_cast<const half8_t*>(ft + (y1 * Wd + x0) * 128 + i16 * 8);
  half8_t v11 = *reinterpret_cast<const half8_t*>(ft + (y1 * Wd + x1) * 128 + i16 * 8);
  half8_t top = v00 + wx * (v01 - v00);
  half8_t bot = v10 + wx * (v11 - v10);
  half8_t r = top + wy * (bot - top);
  *reinterpret_cast<half8_t*>(dstRow + i16 * 8) = r;
}

// 64-row x 128-col matvec slice via MFMA 16x16x32 fp16, 8 waves split N (nt=w),
// 4 row-fragments per wave, acc = 16 f32 (AGPR-lean). Sources/dest are u16
// buffers (LDS or global) with given strides.
template <int KT, int SPLITKT, int ACT, int NWAVES = 8>
__device__ __forceinline__ void mmv(
    const u16* __restrict__ wpk,
    const u16* aA, int strA, const u16* aB, int strB,
    const float* __restrict__ bias,
    u16* ob, int ostr) {
  const int tid = threadIdx.x;
  const int lane = tid & 63;
  const int w = tid >> 6;
  const int l15 = lane & 15;
  const int g = lane >> 4;
  if (NWAVES == 8 || w < NWAVES) {
    f32x4_t acc[4];
#pragma unroll
    for (int mt = 0; mt < 4; ++mt) acc[mt] = (f32x4_t){0.f, 0.f, 0.f, 0.f};
#pragma unroll
    for (int kt = 0; kt < KT; ++kt) {
      const u16* ab = (kt < SPLITKT) ? (aA + kt * 32) : (aB + (kt - SPLITKT) * 32);
      const int str = (kt < SPLITKT) ? strA : strB;
      half8_t af[4];
#pragma unroll
      for (int mt = 0; mt < 4; ++mt)
        af[mt] = *reinterpret_cast<const half8_t*>(ab + (mt * 16 + l15) * str + g * 8);
      half8_t bf = *reinterpret_cast<const half8_t*>(wpk + ((w * KT + kt) * 64 + lane) * 8);
#pragma unroll
      for (int mt = 0; mt < 4; ++mt)
        acc[mt] = __builtin_amdgcn_mfma_f32_16x16x32_f16(bf, af[mt], acc[mt], 0, 0, 0);
    }
    const int colg = w << 4;
    f32x4_t bv = *reinterpret_cast<const f32x4_t*>(bias + colg + (g << 2));
#pragma unroll
    for (int mt = 0; mt < 4; ++mt) {
      const int row = (mt << 4) + l15;
      half4_t hv;
#pragma unroll
      for (int r = 0; r < 4; ++r) {
        float v = acc[mt][r] + bv[r];
        if (ACT == 1) v = geluf(v);
        hv[r] = (_Float16)v;
      }
      *reinterpret_cast<half4_t*>(ob + row * ostr + colg + (g << 2)) = hv;
    }
  }
}

// layernorm rows of src [64][SAB] -> dst [64][SHB] cols 0..127 (8 threads/row)
__device__ __forceinline__ void lnorm(const u16* src, u16* dst,
                                      const float* __restrict__ lw,
                                      const float* __restrict__ lb) {
  const int tid = threadIdx.x;
  int q = tid >> 3, s = tid & 7;
  const u16* rp = src + q * SAB + s * 16;
  float xs[16];
  float sum = 0.f, sum2 = 0.f;
#pragma unroll
  for (int c8 = 0; c8 < 2; ++c8) {
    half8_t v = *reinterpret_cast<const half8_t*>(rp + c8 * 8);
#pragma unroll
    for (int j = 0; j < 8; ++j) {
      float x = (float)v[j];
      xs[c8 * 8 + j] = x; sum += x; sum2 += x * x;
    }
  }
  sum += __shfl_xor(sum, 1); sum2 += __shfl_xor(sum2, 1);
  sum += __shfl_xor(sum, 2); sum2 += __shfl_xor(sum2, 2);
  sum += __shfl_xor(sum, 4); sum2 += __shfl_xor(sum2, 4);
  float mean = sum * 0.0078125f;
  float var = sum2 * 0.0078125f - mean * mean;
  float rstd = rsqrtf(var + 1e-5f);
  u16* op = dst + q * SHB + s * 16;
#pragma unroll
  for (int c8 = 0; c8 < 2; ++c8) {
    half8_t r;
#pragma unroll
    for (int j = 0; j < 8; ++j) {
      int c = s * 16 + c8 * 8 + j;
      r[j] = (_Float16)((xs[c8 * 8 + j] - mean) * rstd * lw[c] + lb[c]);
    }
    *reinterpret_cast<half8_t*>(op + c8 * 8) = r;
  }
}

// ---------------- prep kernels ----------------
__global__ void compose1(const float* __restrict__ pp_w2, const float* __restrict__ f1_ph_w,
                         const float* __restrict__ f1_gate, const float* __restrict__ f2_ph_w,
                         const float* __restrict__ f2_gate, const float* __restrict__ p8_b,
                         const float* __restrict__ f1_ph_b, const float* __restrict__ pp_b2,
                         float* __restrict__ Wbot1, float* __restrict__ Wph2s,
                         float* __restrict__ bf1) {
  int idx = blockIdx.x * blockDim.x + threadIdx.x;
  if (idx >= 16384) return;
  int k = idx >> 7, m = idx & 127;
  float sig1 = 1.f / (1.f + expf(-f1_gate[m]));
  float acc = 0.f;
  for (int r = 0; r < 128; ++r) acc += pp_w2[k * 128 + r] * f1_ph_w[r * 128 + m];
  Wbot1[idx] = acc * sig1;
  Wph2s[idx] = f2_ph_w[idx] * (1.f / (1.f + expf(-f2_gate[m])));
  if (k == 0) {
    float b = 0.f;
    for (int r = 0; r < 128; ++r) b += pp_b2[r] * f1_ph_w[r * 128 + m];
    bf1[m] = p8_b[m] + sig1 * f1_ph_b[m] + sig1 * b;
  }
}

__global__ void biasAB(const float* __restrict__ bf1, const float* __restrict__ f1_w1,
                       const float* __restrict__ f1_b1, const float* __restrict__ p16_b,
                       const float* __restrict__ f2_ph_b, const float* __restrict__ f2_gate,
                       const float* __restrict__ f2_w1, const float* __restrict__ f2_b1,
                       float* __restrict__ bA, float* __restrict__ bB) {
  int n = threadIdx.x;
  if (n < 256) {
    float acc = f1_b1[n];
    for (int m = 0; m < 128; ++m) acc += bf1[m] * f1_w1[m * 256 + n];
    bA[n] = acc;
  } else {
    int n2 = n - 256;
    float acc = f2_b1[n2];
    for (int m = 0; m < 128; ++m) {
      float sig2 = 1.f / (1.f + expf(-f2_gate[m]));
      acc += (p16_b[m] + sig2 * f2_ph_b[m]) * f2_w1[m * 256 + n2];
    }
    bB[n2] = acc;
  }
}

struct PackArgs {
  const float *pp_w1, *p8_w, *f1_w1, *f1_w2, *p16_w, *f2_w1, *f2_w2, *h_w1, *h_w2;
  const float *Wbot1, *Wph2s;
  u16* dst;
};

__global__ void pack_weights(PackArgs a) {
  const int KTs[7]   = {3, 8, 8, 8, 8, 5, 4};
  const int Ks[7]    = {75, 256, 256, 256, 256, 156, 128};
  const int bases[8] = {0, 12288, 77824, 110592, 176128, 208896, 229376, 237568};
  int stride = gridDim.x * blockDim.x;
  for (int i = blockIdx.x * blockDim.x + threadIdx.x; i < PW_END; i += stride) {
    int s = 0;
    while (i >= bases[s + 1]) ++s;
    int rem = i - bases[s];
    int e = rem & 511, lane = e >> 3, j = e & 7;
    int ntkt = rem >> 9;
    int kt = ntkt % KTs[s], nt = ntkt / KTs[s];
    int k = kt * 32 + ((lane >> 4) << 3) + j;
    int col = (nt << 4) + (lane & 15);
    float v = 0.f;
    if (k < Ks[s]) {
      switch (s) {
        case 0: v = a.pp_w1[k * 128 + col]; break;
        case 1: {  // WA = [p8_w ; Wbot1] @ f1_w1   (256 x 256)
          float acc = 0.f;
          if (k < 128) {
            for (int m = 0; m < 128; ++m) acc += a.p8_w[k * 128 + m] * a.f1_w1[m * 256 + col];
          } else {
            for (int m = 0; m < 128; ++m) acc += a.Wbot1[(k - 128) * 128 + m] * a.f1_w1[m * 256 + col];
          }
          v = acc;
        } break;
        case 2: v = a.f1_w2[k * 128 + col]; break;
        case 3: {  // WB = [p16_w ; Wph2s] @ f2_w1   (256 x 256)
          float acc = 0.f;
          if (k < 128) {
            for (int m = 0; m < 128; ++m) acc += a.p16_w[k * 128 + m] * a.f2_w1[m * 256 + col];
          } else {
            for (int m = 0; m < 128; ++m) acc += a.Wph2s[(k - 128) * 128 + m] * a.f2_w1[m * 256 + col];
          }
          v = acc;
        } break;
        case 4: v = a.f2_w2[k * 128 + col]; break;
        case 5: v = a.h_w1[k * 128 + col]; break;
        case 6: v = a.h_w2[k * 64 + col]; break;
      }
    }
    a.dst[i] = tohalf(v);
  }
}

__global__ void cvt_cl_f16(const float* __restrict__ src, u16* __restrict__ dst,
                           int Hd, int Wd) {
  int total = 2 * 128 * Hd * Wd;
  int stride = gridDim.x * blockDim.x;
  for (int i = blockIdx.x * blockDim.x + threadIdx.x; i < total; i += stride) {
    int x = i % Wd;
    int t = i / Wd;
    int y = t % Hd; t /= Hd;
    int c = t % 128;
    int b = t / 128;
    dst[((b * Hd + y) * Wd + x) * 128 + c] = tohalf(src[i]);
  }
}

// ---------------- main fused kernel (11 phases, 3 LDS buffers) ----------------
struct KParams {
  const float *img, *coarse_flow, *qc;
  const u16 *wpk, *ft8, *ft16;
  const float *bA, *bB;
  u16* peg;      // [2048][64][40] pe/coarse staging (global, L3-resident)
  float* cbg;    // [2048][64][2]
  u16* wg;       // [2048][64][128] wide-half staging (global, L2-resident)
  const float *pp_b1;
  const float *f1_b2, *f1_ln_w, *f1_ln_b;
  const float *f2_b2, *f2_ln_w, *f2_ln_b;
  const float *h_b1, *h_b2, *h_w3, *h_b3;
  float* out;
};

__global__ __launch_bounds__(NT, 2) void ifd_mfma(KParams P) {
  __shared__ __align__(16) u16 smem[3 * MB * SAB];   // 52224 B -> 2 blocks/CU
  u16* ab0 = smem;
  u16* ab1 = smem + MB * SAB;
  u16* hb  = smem + 2 * MB * SAB;

  const int tid = threadIdx.x;
  const int m0 = blockIdx.x * MB;
  u16* pegB = P.peg + blockIdx.x * (MB * SPE);
  float* cbgB = P.cbg + blockIdx.x * (MB * 2);
  u16* wgB = P.wg + blockIdx.x * (MB * SWG);

  // ---- Ph1: patches -> ab0[0..95]; pe/coarse -> peg + cbg ----
  {
    const int q = tid >> 3, sub = tid & 7;
    const int m = m0 + q, b = m >> 16;
    const float qx = P.qc[2 * m], qy = P.qc[2 * m + 1];
    const float* imgb = P.img + b * 3 * (IMG_H * IMG_W);
#pragma unroll
    for (int j = 0; j < 12; ++j) {
      const int c = sub * 12 + j;
      u16 val = 0;
      if (c < 75) {
        int p = c / 3, ch = c - p * 3;
        int iy = p / 5, ix = p - iy * 5;
        val = tohalf(bilin_plane(imgb + ch * (IMG_H * IMG_W), IMG_W, IMG_H,
                                 qx + (float)(ix - 2), qy + (float)(iy - 2)));
      }
      ab0[q * SAB + c] = val;
    }
  }
  if (tid < 128) {  // pe via angle doubling
    const int q = tid >> 1, dim = tid & 1;
    const int m = m0 + q;
    const float qv = P.qc[2 * m + dim];
    const float q8 = qv * 0.125f;
    const float loc = (q8 - rintf(q8)) * 2.f;
    pegB[q * SPE + dim] = tohalf(loc);
    const float th = loc * 3.14159265358979323846f;
    float s = __sinf(th), c = __cosf(th);
    const int base = q * SPE + 2 + dim * 12;
#pragma unroll
    for (int bnd = 0; bnd < 6; ++bnd) {
      pegB[base + bnd] = tohalf(s);
      pegB[base + 6 + bnd] = tohalf(c);
      float s2 = 2.f * s * c;
      c = fmaf(-2.f * s, s, 1.f);
      s = s2;
    }
  } else if (tid < 256) {  // coarse
    const int t2 = tid - 128, q = t2 >> 1, o = t2 & 1;
    const int m = m0 + q, b = m >> 16;
    const float qx = P.qc[2 * m], qy = P.qc[2 * m + 1];
    const float x8 = qx * (63.f / 511.f), y8 = qy * (47.f / 383.f);
    const float cv = 8.f * bilin_plane(P.coarse_flow + (b * 2 + o) * (H8 * W8),
                                       W8, H8, x8, y8);
    pegB[q * SPE + 26 + o] = tohalf(cv);
    cbgB[q * 2 + o] = cv;
  } else if (tid < 384) {  // zero peg cols 28..31 (kt4 pad)
    const int t2 = tid - 256, q = t2 >> 1, pr = t2 & 1;
    *reinterpret_cast<unsigned int*>(pegB + q * SPE + 28 + 2 * pr) = 0u;
  }
  __syncthreads();

  // ---- Ph2: S1 (ab0 -> ab1) || samp8 -> hb ----
  mmv<3, 3, 1>(P.wpk + PW_PP1, ab0, SAB, ab0, SAB, P.pp_b1, ab1, SAB);
  for (int i = tid; i < MB * 16; i += NT) {
    int q = i >> 4, i16 = i & 15;
    int m = m0 + q, b = m >> 16;
    float x = P.qc[2 * m] * (63.f / 511.f), y = P.qc[2 * m + 1] * (47.f / 383.f);
    featSample(P.ft8 + b * (H8 * W8 * 128), W8, H8, x, y, hb + q * SHB, i16);
  }
  __syncthreads();

  // ---- Ph3: MEGA1: wide = gelu([samp8(hb) | t1(ab1)] @ WA + bA) -> [ab0 | wg] ----
  mmv<8, 4, 1>(P.wpk + PW_MEGA1, hb, SHB, ab1, SAB, P.bA, ab0, SAB);
  mmv<8, 4, 1>(P.wpk + PW_MEGA1 + 32768, hb, SHB, ab1, SAB, P.bA + 128, wgB, SWG);
  __syncthreads();

  // ---- Ph4: S8: [ab0 | wg] @ f1_w2 + f1_b2 -> ab1 ----
  mmv<8, 4, 0>(P.wpk + PW_S8, ab0, SAB, wgB, SWG, P.f1_b2, ab1, SAB);
  __syncthreads();

  // ---- Ph5: LN1 (ab1 -> hb) || samp16 -> ab0 ----
  lnorm(ab1, hb, P.f1_ln_w, P.f1_ln_b);
  for (int i = tid; i < MB * 16; i += NT) {
    int q = i >> 4, i16 = i & 15;
    int m = m0 + q, b = m >> 16;
    float x = P.qc[2 * m] * (31.f / 511.f), y = P.qc[2 * m + 1] * (23.f / 383.f);
    featSample(P.ft16 + b * (H16 * W16 * 128), W16, H16, x, y, ab0 + q * SAB, i16);
  }
  __syncthreads();

  // ---- Ph6: MEGA2: wide2 = gelu([samp16(ab0) | h2(hb)] @ WB + bB) -> [ab1 | wg] ----
  mmv<8, 4, 1>(P.wpk + PW_MEGA2, ab0, SAB, hb, SHB, P.bB, ab1, SAB);
  mmv<8, 4, 1>(P.wpk + PW_MEGA2 + 32768, ab0, SAB, hb, SHB, P.bB + 128, wgB, SWG);
  __syncthreads();

  // ---- Ph7: S15: [ab1 | wg] @ f2_w2 + f2_b2 -> ab0 ----
  mmv<8, 4, 0>(P.wpk + PW_S15, ab1, SAB, wgB, SWG, P.f2_b2, ab0, SAB);
  __syncthreads();

  // ---- Ph8: LN2: ab0 -> hb ----
  lnorm(ab0, hb, P.f2_ln_w, P.f2_ln_b);
  __syncthreads();

  // ---- Ph9: S18: gelu([hb | peg] @ h_w1 + h_b1) -> ab1  (K=160) ----
  mmv<5, 4, 1>(P.wpk + PW_HW1, hb, SHB, pegB, SPE, P.h_b1, ab1, SAB);
  __syncthreads();

  // ---- Ph10: S19: gelu(ab1 @ h_w2 + h_b2) -> ab0[0..63]  (waves 0-3) ----
  mmv<4, 4, 1, 4>(P.wpk + PW_HW2, ab1, SAB, ab1, SAB, P.h_b2, ab0, SAB);
  __syncthreads();

  // ---- Ph11: S20: out = coarse + (g @ h_w3 + h_b3) ----
  if (tid < 2 * MB) {
    int q = tid >> 1, o = tid & 1;
    float acc = P.h_b3[o];
    const u16* rp = ab0 + q * SAB;
#pragma unroll
    for (int c8 = 0; c8 < 8; ++c8) {
      half8_t v = *reinterpret_cast<const half8_t*>(rp + c8 * 8);
#pragma unroll
      for (int j = 0; j < 8; ++j) acc += (float)v[j] * P.h_w3[(c8 * 8 + j) * 2 + o];
    }
    P.out[(m0 + q) * 2 + o] = cbgB[q * 2 + o] + acc;
  }
}

extern "C" void kernel_launch(void* const* d_in, const int* in_sizes, int n_in,
                              void* d_out, int out_size, void* d_ws, size_t ws_size,
                              hipStream_t stream) {
  u16* wp = (u16*)d_ws;
  float* fbase = (float*)(wp + F32_OFF);
  float* Wbot1 = fbase;
  float* Wph2s = fbase + 16384;
  float* bf1   = fbase + 32768;
  float* bA    = fbase + 32896;
  float* bB    = fbase + 33152;
  u16* peg = wp + PEG_OFF;
  float* cbg = (float*)(wp + CBG_OFF);
  u16* wg  = wp + WG_OFF;

  const float* pp_w2   = (const float*)d_in[7];
  const float* f1_ph_w = (const float*)d_in[13];
  const float* f1_gate = (const float*)d_in[15];
  const float* f2_ph_w = (const float*)d_in[22];
  const float* f2_gate = (const float*)d_in[24];

  compose1<<<64, 256, 0, stream>>>(pp_w2, f1_ph_w, f1_gate, f2_ph_w, f2_gate,
                                   (const float*)d_in[10], (const float*)d_in[14],
                                   (const float*)d_in[8], Wbot1, Wph2s, bf1);
  biasAB<<<1, 512, 0, stream>>>(bf1, (const float*)d_in[16], (const float*)d_in[17],
                                (const float*)d_in[12], (const float*)d_in[23],
                                f2_gate, (const float*)d_in[25], (const float*)d_in[26],
                                bA, bB);

  PackArgs pa;
  pa.pp_w1 = (const float*)d_in[5];
  pa.p8_w  = (const float*)d_in[9];
  pa.f1_w1 = (const float*)d_in[16];
  pa.f1_w2 = (const float*)d_in[18];
  pa.p16_w = (const float*)d_in[11];
  pa.f2_w1 = (const float*)d_in[25];
  pa.f2_w2 = (const float*)d_in[27];
  pa.h_w1  = (const float*)d_in[31];
  pa.h_w2  = (const float*)d_in[33];
  pa.Wbot1 = Wbot1; pa.Wph2s = Wph2s;
  pa.dst = wp;
  pack_weights<<<928, 256, 0, stream>>>(pa);
  cvt_cl_f16<<<1024, 256, 0, stream>>>((const float*)d_in[1], wp + FT8_OFF, H8, W8);
  cvt_cl_f16<<<256, 256, 0, stream>>>((const float*)d_in[2], wp + FT16_OFF, H16, W16);

  KParams P;
  P.img = (const float*)d_in[0];
  P.coarse_flow = (const float*)d_in[3];
  P.qc = (const float*)d_in[4];
  P.wpk = wp; P.ft8 = wp + FT8_OFF; P.ft16 = wp + FT16_OFF;
  P.bA = bA; P.bB = bB;
  P.peg = peg; P.cbg = cbg; P.wg = wg;
  P.pp_b1 = (const float*)d_in[6];
  P.f1_b2 = (const float*)d_in[19];
  P.f1_ln_w = (const float*)d_in[20]; P.f1_ln_b = (const float*)d_in[21];
  P.f2_b2 = (const float*)d_in[28];
  P.f2_ln_w = (const float*)d_in[29]; P.f2_ln_b = (const float*)d_in[30];
  P.h_b1 = (const float*)d_in[32]; P.h_b2 = (const float*)d_in[34];
  P.h_w3 = (const float*)d_in[35]; P.h_b3 = (const float*)d_in[36];
  P.out = (float*)d_out;

  ifd_mfma<<<MTOT / MB, NT, 0, stream>>>(P);
}

// Round 17
// 181.871 us; speedup vs baseline: 1.7938x; 1.7938x over previous
//
#include <hip/hip_runtime.h>
#include <math.h>

#define NT 512           // 8 waves
#define MB 64            // queries per block
#define MTOT 131072
#define IMG_H 384
#define IMG_W 512
#define H8 48
#define W8 64
#define H16 24
#define W16 32

#define SAB 136          // ab0/ab1/hb row stride (u16)
#define SHB 136
#define SPE 40           // pe row stride (u16), global scratch

typedef _Float16 half8_t __attribute__((ext_vector_type(8)));
typedef _Float16 half4_t __attribute__((ext_vector_type(4)));
typedef float f32x4_t __attribute__((ext_vector_type(4)));
typedef unsigned short u16;

// packed weight fragment order: ((nt*KT + kt)*64 + lane)*8 + j
// element = W[kt*32 + (lane>>4)*8 + j][nt*16 + (lane&15)]
#define PW_PP1    0
#define PW_PP2    12288
#define PW_P8CAT  28672
#define PW_P16CAT 61440
#define PW_F1W1   94208
#define PW_F1W2   126976
#define PW_F2W1   159744
#define PW_F2W2   192512
#define PW_HW1    225280
#define PW_HW2    245760
#define PW_END    253952
#define FT8_OFF   PW_END
#define FT8_CNT   (2*H8*W8*128)
#define FT16_OFF  (FT8_OFF + FT8_CNT)
#define FT16_CNT  (2*H16*W16*128)
#define FB_OFF    (FT16_OFF + FT16_CNT)        // 256 floats (fused biases)
#define PEG_OFF   (FB_OFF + 512)               // u16 [2048][64][40]
#define PEG_CNT   (2048*MB*SPE)
#define CBG_OFF   (PEG_OFF + PEG_CNT)          // f32 [2048][64][2]

__device__ __forceinline__ u16 tohalf(float v) {
  return __builtin_bit_cast(u16, (_Float16)v);
}
// tanh-form gelu; |err vs exact erf-gelu| < 3e-3
__device__ __forceinline__ float geluf(float x) {
  float x2 = x * x;
  float t = x * fmaf(x2, 0.0713548162726f, 1.5957691216057308f);
  float e = __expf(-t);
  return x * __builtin_amdgcn_rcpf(1.0f + e);
}

__device__ __forceinline__ float bilin_plane(const float* __restrict__ plane,
                                             int Wd, int Hd, float x, float y) {
  x = fminf(fmaxf(x, 0.f), (float)(Wd - 1));
  y = fminf(fmaxf(y, 0.f), (float)(Hd - 1));
  float x0f = floorf(x), y0f = floorf(y);
  int x0 = (int)x0f, y0 = (int)y0f;
  int x1 = min(x0 + 1, Wd - 1), y1 = min(y0 + 1, Hd - 1);
  float wx = x - x0f, wy = y - y0f;
  const float* r0 = plane + y0 * Wd;
  const float* r1 = plane + y1 * Wd;
  float v00 = r0[x0], v01 = r0[x1], v10 = r1[x0], v11 = r1[x1];
  float top = v00 + wx * (v01 - v00);
  float bot = v10 + wx * (v11 - v10);
  return top + wy * (bot - top);
}

// bilinear gather of 8 fp16 channels, packed-f16 interpolation
__device__ __forceinline__ void featSample(const u16* __restrict__ ft, int Wd, int Hd,
                                           float x, float y, u16* dstRow, int i16) {
  x = fminf(fmaxf(x, 0.f), (float)(Wd - 1));
  y = fminf(fmaxf(y, 0.f), (float)(Hd - 1));
  float x0f = floorf(x), y0f = floorf(y);
  int x0 = (int)x0f, y0 = (int)y0f;
  int x1 = min(x0 + 1, Wd - 1), y1 = min(y0 + 1, Hd - 1);
  _Float16 wx = (_Float16)(x - x0f), wy = (_Float16)(y - y0f);
  half8_t v00 = *reinterpret_cast<const half8_t*>(ft + (y0 * Wd + x0) * 128 + i16 * 8);
  half8_t v01 = *reinterpret_cast<const half8_t*>(ft + (y0 * Wd + x1) * 128 + i16 * 8);
  half8_t v10 = *reinterpret_cast<const half8_t*>(ft + (y1 * Wd + x0) * 128 + i16 * 8);
  half8_t v11 = *reinterpret_cast<const half8_t*>(ft + (y1 * Wd + x1) * 128 + i16 * 8);
  half8_t top = v00 + wx * (v01 - v00);
  half8_t bot = v10 + wx * (v11 - v10);
  half8_t r = top + wy * (bot - top);
  *reinterpret_cast<half8_t*>(dstRow + i16 * 8) = r;
}

// 64-row x 128-col matvec slice via MFMA 16x16x32 fp16, 8 waves split N (nt=w),
// 4 row-fragments per wave, acc = 16 f32. s_setprio(1) around the MFMA k-loop
// (T5): with 2 independent blocks/CU at different phases, MFMA waves preempt
// the other block's sampling/gelu VALU bursts.
template <int KT, int SPLITKT, int ACT, int NWAVES = 8>
__device__ __forceinline__ void mmv(
    const u16* __restrict__ wpk,
    const u16* aA, int strA, const u16* aB, int strB,
    const float* __restrict__ bias,
    u16* ob, int ostr) {
  const int tid = threadIdx.x;
  const int lane = tid & 63;
  const int w = tid >> 6;
  const int l15 = lane & 15;
  const int g = lane >> 4;
  if (NWAVES == 8 || w < NWAVES) {
    f32x4_t acc[4];
#pragma unroll
    for (int mt = 0; mt < 4; ++mt) acc[mt] = (f32x4_t){0.f, 0.f, 0.f, 0.f};
    __builtin_amdgcn_s_setprio(1);
#pragma unroll
    for (int kt = 0; kt < KT; ++kt) {
      const u16* ab = (kt < SPLITKT) ? (aA + kt * 32) : (aB + (kt - SPLITKT) * 32);
      const int str = (kt < SPLITKT) ? strA : strB;
      half8_t af[4];
#pragma unroll
      for (int mt = 0; mt < 4; ++mt)
        af[mt] = *reinterpret_cast<const half8_t*>(ab + (mt * 16 + l15) * str + g * 8);
      half8_t bf = *reinterpret_cast<const half8_t*>(wpk + ((w * KT + kt) * 64 + lane) * 8);
#pragma unroll
      for (int mt = 0; mt < 4; ++mt)
        acc[mt] = __builtin_amdgcn_mfma_f32_16x16x32_f16(bf, af[mt], acc[mt], 0, 0, 0);
    }
    __builtin_amdgcn_s_setprio(0);
    const int colg = w << 4;
    f32x4_t bv = *reinterpret_cast<const f32x4_t*>(bias + colg + (g << 2));
#pragma unroll
    for (int mt = 0; mt < 4; ++mt) {
      const int row = (mt << 4) + l15;
      half4_t hv;
#pragma unroll
      for (int r = 0; r < 4; ++r) {
        float v = acc[mt][r] + bv[r];
        if (ACT == 1) v = geluf(v);
        hv[r] = (_Float16)v;
      }
      *reinterpret_cast<half4_t*>(ob + row * ostr + colg + (g << 2)) = hv;
    }
  }
}

// layernorm rows of src [64][SAB] -> dst [64][SHB] cols 0..127 (8 threads/row)
__device__ __forceinline__ void lnorm(const u16* src, u16* dst,
                                      const float* __restrict__ lw,
                                      const float* __restrict__ lb) {
  const int tid = threadIdx.x;
  int q = tid >> 3, s = tid & 7;
  const u16* rp = src + q * SAB + s * 16;
  float xs[16];
  float sum = 0.f, sum2 = 0.f;
#pragma unroll
  for (int c8 = 0; c8 < 2; ++c8) {
    half8_t v = *reinterpret_cast<const half8_t*>(rp + c8 * 8);
#pragma unroll
    for (int j = 0; j < 8; ++j) {
      float x = (float)v[j];
      xs[c8 * 8 + j] = x; sum += x; sum2 += x * x;
    }
  }
  sum += __shfl_xor(sum, 1); sum2 += __shfl_xor(sum2, 1);
  sum += __shfl_xor(sum, 2); sum2 += __shfl_xor(sum2, 2);
  sum += __shfl_xor(sum, 4); sum2 += __shfl_xor(sum2, 4);
  float mean = sum * 0.0078125f;
  float var = sum2 * 0.0078125f - mean * mean;
  float rstd = rsqrtf(var + 1e-5f);
  u16* op = dst + q * SHB + s * 16;
#pragma unroll
  for (int c8 = 0; c8 < 2; ++c8) {
    half8_t r;
#pragma unroll
    for (int j = 0; j < 8; ++j) {
      int c = s * 16 + c8 * 8 + j;
      r[j] = (_Float16)((xs[c8 * 8 + j] - mean) * rstd * lw[c] + lb[c]);
    }
    *reinterpret_cast<half8_t*>(op + c8 * 8) = r;
  }
}

// ---------------- prep kernels ----------------
struct PackArgs {
  const float *pp_w1, *pp_w2, *p8_w, *f1_ph_w, *f1_gate, *p16_w, *f2_ph_w, *f2_gate;
  const float *f1_w1, *f1_w2, *f2_w1, *f2_w2, *h_w1, *h_w2;
  u16* dst;
};

__global__ void pack_weights(PackArgs a) {
  const int KTs[10]   = {3, 4, 8, 8, 4, 8, 4, 8, 5, 4};
  const int Ks[10]    = {75, 128, 256, 256, 128, 256, 128, 256, 156, 128};
  const int bases[11] = {0, 12288, 28672, 61440, 94208, 126976,
                         159744, 192512, 225280, 245760, 253952};
  int stride = gridDim.x * blockDim.x;
  for (int i = blockIdx.x * blockDim.x + threadIdx.x; i < PW_END; i += stride) {
    int s = 0;
    while (i >= bases[s + 1]) ++s;
    int rem = i - bases[s];
    int e = rem & 511, lane = e >> 3, j = e & 7;
    int ntkt = rem >> 9;
    int kt = ntkt % KTs[s], nt = ntkt / KTs[s];
    int k = kt * 32 + ((lane >> 4) << 3) + j;
    int col = (nt << 4) + (lane & 15);
    float v = 0.f;
    if (k < Ks[s]) {
      switch (s) {
        case 0: v = a.pp_w1[k * 128 + col]; break;
        case 1: v = a.pp_w2[k * 128 + col]; break;
        case 2: v = (k < 128) ? a.p8_w[k * 128 + col]
                              : a.f1_ph_w[(k - 128) * 128 + col] /
                                    (1.f + expf(-a.f1_gate[col])); break;
        case 3: v = (k < 128) ? a.p16_w[k * 128 + col]
                              : a.f2_ph_w[(k - 128) * 128 + col] /
                                    (1.f + expf(-a.f2_gate[col])); break;
        case 4: v = a.f1_w1[k * 256 + col]; break;
        case 5: v = a.f1_w2[k * 128 + col]; break;
        case 6: v = a.f2_w1[k * 256 + col]; break;
        case 7: v = a.f2_w2[k * 128 + col]; break;
        case 8: v = a.h_w1[k * 128 + col]; break;
        case 9: v = a.h_w2[k * 64 + col]; break;
      }
    }
    a.dst[i] = tohalf(v);
  }
}

__global__ void fuse_bias(const float* __restrict__ p8_b, const float* __restrict__ f1_ph_b,
                          const float* __restrict__ f1_gate,
                          const float* __restrict__ p16_b, const float* __restrict__ f2_ph_b,
                          const float* __restrict__ f2_gate, float* __restrict__ fb) {
  int t = threadIdx.x;
  if (t < 128) {
    fb[t] = p8_b[t] + f1_ph_b[t] / (1.f + expf(-f1_gate[t]));
    fb[128 + t] = p16_b[t] + f2_ph_b[t] / (1.f + expf(-f2_gate[t]));
  }
}

__global__ void cvt_cl_f16(const float* __restrict__ src, u16* __restrict__ dst,
                           int Hd, int Wd) {
  int total = 2 * 128 * Hd * Wd;
  int stride = gridDim.x * blockDim.x;
  for (int i = blockIdx.x * blockDim.x + threadIdx.x; i < total; i += stride) {
    int x = i % Wd;
    int t = i / Wd;
    int y = t % Hd; t /= Hd;
    int c = t % 128;
    int b = t / 128;
    dst[((b * Hd + y) * Wd + x) * 128 + c] = tohalf(src[i]);
  }
}

// ---------------- main fused kernel ----------------
struct KParams {
  const float *img, *coarse_flow, *qc;
  const u16 *wpk, *ft8, *ft16;
  const float *fb;
  u16* peg;      // [2048][64][40] pe/coarse staging (global, L3-resident)
  float* cbg;    // [2048][64][2]
  const float *pp_b1, *pp_b2;
  const float *f1_b1, *f1_b2, *f1_ln_w, *f1_ln_b;
  const float *f2_b1, *f2_b2, *f2_ln_w, *f2_ln_b;
  const float *h_b1, *h_b2, *h_w3, *h_b3;
  float* out;
};

__global__ __launch_bounds__(NT, 2) void ifd_mfma(KParams P) {
  __shared__ __align__(16) u16 smem[3 * MB * SAB];   // 52224 B
  u16* ab0 = smem;
  u16* ab1 = smem + MB * SAB;
  u16* hb  = smem + 2 * MB * SAB;

  const int tid = threadIdx.x;
  const int m0 = blockIdx.x * MB;
  u16* pegB = P.peg + blockIdx.x * (MB * SPE);
  float* cbgB = P.cbg + blockIdx.x * (MB * 2);

  // P0a: patches -> ab0 cols 0..95 (each thread: 1 query, 12 cols)
  {
    const int q = tid >> 3, sub = tid & 7;
    const int m = m0 + q, b = m >> 16;
    const float qx = P.qc[2 * m], qy = P.qc[2 * m + 1];
    const float* imgb = P.img + b * 3 * (IMG_H * IMG_W);
#pragma unroll
    for (int j = 0; j < 12; ++j) {
      const int c = sub * 12 + j;
      u16 val = 0;
      if (c < 75) {
        int p = c / 3, ch = c - p * 3;
        int iy = p / 5, ix = p - iy * 5;
        val = tohalf(bilin_plane(imgb + ch * (IMG_H * IMG_W), IMG_W, IMG_H,
                                 qx + (float)(ix - 2), qy + (float)(iy - 2)));
      }
      ab0[q * SAB + c] = val;
    }
  }
  // P0b: pe (0..127), coarse (128..255), zero-pad (256..383)
  if (tid < 128) {
    const int q = tid >> 1, dim = tid & 1;
    const int m = m0 + q;
    const float qv = P.qc[2 * m + dim];
    const float q8 = qv * 0.125f;
    const float loc = (q8 - rintf(q8)) * 2.f;
    pegB[q * SPE + dim] = tohalf(loc);
    const float th = loc * 3.14159265358979323846f;
    float s = __sinf(th), c = __cosf(th);
    const int base = q * SPE + 2 + dim * 12;
#pragma unroll
    for (int bnd = 0; bnd < 6; ++bnd) {
      pegB[base + bnd] = tohalf(s);
      pegB[base + 6 + bnd] = tohalf(c);
      float s2 = 2.f * s * c;
      c = fmaf(-2.f * s, s, 1.f);
      s = s2;
    }
  } else if (tid < 256) {
    const int t2 = tid - 128, q = t2 >> 1, o = t2 & 1;
    const int m = m0 + q, b = m >> 16;
    const float qx = P.qc[2 * m], qy = P.qc[2 * m + 1];
    const float x8 = qx * (63.f / 511.f), y8 = qy * (47.f / 383.f);
    const float cv = 8.f * bilin_plane(P.coarse_flow + (b * 2 + o) * (H8 * W8),
                                       W8, H8, x8, y8);
    pegB[q * SPE + 26 + o] = tohalf(cv);
    cbgB[q * 2 + o] = cv;
  } else if (tid < 384) {
    const int t2 = tid - 256, q = t2 >> 1, pr = t2 & 1;
    *reinterpret_cast<unsigned int*>(pegB + q * SPE + 28 + 2 * pr) = 0u;
  }
  __syncthreads();

  // S1: ab1 = gelu(patches @ pp_w1 + pp_b1)
  mmv<3, 3, 1>(P.wpk + PW_PP1, ab0, SAB, ab0, SAB, P.pp_b1, ab1, SAB);
  __syncthreads();
  // S2: hb(h) = ab1 @ pp_w2 + pp_b2 ; sample f8 -> ab0
  mmv<4, 4, 0>(P.wpk + PW_PP2, ab1, SAB, ab1, SAB, P.pp_b2, hb, SHB);
  for (int i = tid; i < MB * 16; i += NT) {
    int q = i >> 4, i16 = i & 15;
    int m = m0 + q, b = m >> 16;
    float x = P.qc[2 * m] * (63.f / 511.f), y = P.qc[2 * m + 1] * (47.f / 383.f);
    featSample(P.ft8 + b * (H8 * W8 * 128), W8, H8, x, y, ab0 + q * SAB, i16);
  }
  __syncthreads();
  // S45: ab1 = [samp8 | h] @ P8CAT + fb8
  mmv<8, 4, 0>(P.wpk + PW_P8CAT, ab0, SAB, hb, SHB, P.fb, ab1, SAB);
  __syncthreads();
  // S7: wide = gelu(ab1 @ f1_w1 + f1_b1): two 128-col slices (ab0, then hb)
  mmv<4, 4, 1>(P.wpk + PW_F1W1, ab1, SAB, ab1, SAB, P.f1_b1, ab0, SAB);
  mmv<4, 4, 1>(P.wpk + PW_F1W1 + 8 * 4 * 512, ab1, SAB, ab1, SAB, P.f1_b1 + 128,
               hb, SHB);
  __syncthreads();
  // S8: ab1 = wide @ f1_w2 + f1_b2 (K=256)
  mmv<8, 4, 0>(P.wpk + PW_F1W2, ab0, SAB, hb, SHB, P.f1_b2, ab1, SAB);
  __syncthreads();
  // LN1 -> hb ; sample f16 -> ab0
  lnorm(ab1, hb, P.f1_ln_w, P.f1_ln_b);
  for (int i = tid; i < MB * 16; i += NT) {
    int q = i >> 4, i16 = i & 15;
    int m = m0 + q, b = m >> 16;
    float x = P.qc[2 * m] * (31.f / 511.f), y = P.qc[2 * m + 1] * (23.f / 383.f);
    featSample(P.ft16 + b * (H16 * W16 * 128), W16, H16, x, y, ab0 + q * SAB, i16);
  }
  __syncthreads();
  // S1112: ab1 = [samp16 | h'] @ P16CAT + fb16
  mmv<8, 4, 0>(P.wpk + PW_P16CAT, ab0, SAB, hb, SHB, P.fb + 128, ab1, SAB);
  __syncthreads();
  // S14: wide2 = gelu(ab1 @ f2_w1 + f2_b1): two 128-col slices
  mmv<4, 4, 1>(P.wpk + PW_F2W1, ab1, SAB, ab1, SAB, P.f2_b1, ab0, SAB);
  mmv<4, 4, 1>(P.wpk + PW_F2W1 + 8 * 4 * 512, ab1, SAB, ab1, SAB, P.f2_b1 + 128,
               hb, SHB);
  __syncthreads();
  // S15: ab1 = wide2 @ f2_w2 + f2_b2
  mmv<8, 4, 0>(P.wpk + PW_F2W2, ab0, SAB, hb, SHB, P.f2_b2, ab1, SAB);
  __syncthreads();
  // LN2 -> hb
  lnorm(ab1, hb, P.f2_ln_w, P.f2_ln_b);
  __syncthreads();
  // S18: ab1 = gelu(mi @ h_w1 + h_b1)  (kt0..3 = hb(h3), kt4 = peg)
  mmv<5, 4, 1>(P.wpk + PW_HW1, hb, SHB, pegB, SPE, P.h_b1, ab1, SAB);
  __syncthreads();
  // S19: ab0 cols 0..63 = gelu(ab1 @ h_w2 + h_b2)  (waves 0-3)
  mmv<4, 4, 1, 4>(P.wpk + PW_HW2, ab1, SAB, ab1, SAB, P.h_b2, ab0, SAB);
  __syncthreads();
  // S20: out = coarse + (g @ h_w3 + h_b3)
  if (tid < 2 * MB) {
    int q = tid >> 1, o = tid & 1;
    float acc = P.h_b3[o];
    const u16* rp = ab0 + q * SAB;
#pragma unroll
    for (int c8 = 0; c8 < 8; ++c8) {
      half8_t v = *reinterpret_cast<const half8_t*>(rp + c8 * 8);
#pragma unroll
      for (int j = 0; j < 8; ++j) acc += (float)v[j] * P.h_w3[(c8 * 8 + j) * 2 + o];
    }
    P.out[(m0 + q) * 2 + o] = cbgB[q * 2 + o] + acc;
  }
}

extern "C" void kernel_launch(void* const* d_in, const int* in_sizes, int n_in,
                              void* d_out, int out_size, void* d_ws, size_t ws_size,
                              hipStream_t stream) {
  u16* wp = (u16*)d_ws;
  float* fb = (float*)(wp + FB_OFF);
  u16* peg = wp + PEG_OFF;
  float* cbg = (float*)(wp + CBG_OFF);

  PackArgs pa;
  pa.pp_w1  = (const float*)d_in[5];
  pa.pp_w2  = (const float*)d_in[7];
  pa.p8_w   = (const float*)d_in[9];
  pa.p16_w  = (const float*)d_in[11];
  pa.f1_ph_w = (const float*)d_in[13];
  pa.f1_gate = (const float*)d_in[15];
  pa.f1_w1  = (const float*)d_in[16];
  pa.f1_w2  = (const float*)d_in[18];
  pa.f2_ph_w = (const float*)d_in[22];
  pa.f2_gate = (const float*)d_in[24];
  pa.f2_w1  = (const float*)d_in[25];
  pa.f2_w2  = (const float*)d_in[27];
  pa.h_w1   = (const float*)d_in[31];
  pa.h_w2   = (const float*)d_in[33];
  pa.dst = wp;
  pack_weights<<<512, 256, 0, stream>>>(pa);
  fuse_bias<<<1, 128, 0, stream>>>((const float*)d_in[10], (const float*)d_in[14],
                                   (const float*)d_in[15], (const float*)d_in[12],
                                   (const float*)d_in[23], (const float*)d_in[24], fb);
  cvt_cl_f16<<<1024, 256, 0, stream>>>((const float*)d_in[1], wp + FT8_OFF, H8, W8);
  cvt_cl_f16<<<256, 256, 0, stream>>>((const float*)d_in[2], wp + FT16_OFF, H16, W16);

  KParams P;
  P.img = (const float*)d_in[0];
  P.coarse_flow = (const float*)d_in[3];
  P.qc = (const float*)d_in[4];
  P.wpk = wp; P.ft8 = wp + FT8_OFF; P.ft16 = wp + FT16_OFF;
  P.fb = fb; P.peg = peg; P.cbg = cbg;
  P.pp_b1 = (const float*)d_in[6];  P.pp_b2 = (const float*)d_in[8];
  P.f1_b1 = (const float*)d_in[17]; P.f1_b2 = (const float*)d_in[19];
  P.f1_ln_w = (const float*)d_in[20]; P.f1_ln_b = (const float*)d_in[21];
  P.f2_b1 = (const float*)d_in[26]; P.f2_b2 = (const float*)d_in[28];
  P.f2_ln_w = (const float*)d_in[29]; P.f2_ln_b = (const float*)d_in[30];
  P.h_b1 = (const float*)d_in[32]; P.h_b2 = (const float*)d_in[34];
  P.h_w3 = (const float*)d_in[35]; P.h_b3 = (const float*)d_in[36];
  P.out = (float*)d_out;

  ifd_mfma<<<MTOT / MB, NT, 0, stream>>>(P);
}